// Round 7
// baseline (249.550 us; speedup 1.0000x reference)
//
#include <hip/hip_runtime.h>
#include <hip/hip_bf16.h>
#include <cstdint>

#define SEQ  4096
#define DIM  64
#define NBH  64       // B*H
#define FEPS 1e-6f
#define MSTRIDE 4160  // 64*64 M + 64 ksum
#define PITCH 20      // words per transposed-LDS row: 16 data (32 s as bf16 pairs) + 4 pad

typedef __attribute__((ext_vector_type(8))) short bf16x8;
typedef __attribute__((ext_vector_type(4))) float f32x4;

__device__ __forceinline__ float featmap(float x) {
    // relu(sinh(x)); sinh monotone odd so relu(sinh) = sinh(x) for x>0 else 0
    return x > 0.0f ? 0.5f * (__expf(x) - __expf(-x)) : 0.0f;
}

__device__ __forceinline__ unsigned int f2bf_u(float x) {
    // round-to-nearest-even fp32 -> bf16 (inputs finite, no NaN here)
    unsigned int u = __float_as_uint(x);
    u += 0x7fffu + ((u >> 16) & 1u);
    return u >> 16;
}
__device__ __forceinline__ unsigned int pack2(float lo, float hi) {
    return f2bf_u(lo) | (f2bf_u(hi) << 16);   // short[0]=lo (even s), short[1]=hi
}

// ---------------------------------------------------------------------------
// Phase 1: per (chunk, bh) block computes partial M[64][64] = Kf^T V over its
// S-chunk, plus ksum[64]. Coalesced float4 global loads -> in-register
// featmap + bf16 pack -> TRANSPOSED [d][s] LDS tiles (pitch 20 words: rows
// 16B-aligned for b128; writes 2 lanes/bank = free; b128 reads uniform) ->
// MFMA frags are single ds_read_b128. Double-buffered, 1 barrier/tile.
// Fragment values bit-identical to the round-6 kernel (same featmap/RNE).
// ---------------------------------------------------------------------------
__global__ __launch_bounds__(256, 4) void k_phase1(
    const float* __restrict__ K, const float* __restrict__ V,
    const int* __restrict__ mask, float* __restrict__ partM,
    int nchunk, int rows_per_chunk)
{
    const int chunk = blockIdx.x;
    const int bh    = blockIdx.y;
    const int b     = bh >> 4;           // H = 16
    const int tid   = threadIdx.x;
    const int wave  = tid >> 6;
    const int lane  = tid & 63;
    const int r     = lane & 15;         // fragment row/col
    const int g     = lane >> 4;         // k-group
    const int p     = tid & 15;          // staging: s-pair index (s = 2p, 2p+1)
    const int d0    = (tid >> 4) * 4;    // staging: d-column base

    __shared__ unsigned int lds[5120];   // KT0 | VT0 | KT1 | VT1, 1280 words each

    const float* Kb = K + (size_t)bh * SEQ * DIM;
    const float* Vb = V + (size_t)bh * SEQ * DIM;
    const int*   mb = mask + (size_t)b * SEQ;

    const int s0    = chunk * rows_per_chunk;
    const int ntile = rows_per_chunk >> 5;   // 32 s-rows per tile

    f32x4 acc[4];
    #pragma unroll
    for (int nt = 0; nt < 4; ++nt) acc[nt] = (f32x4){0.f, 0.f, 0.f, 0.f};
    float ksum4[4] = {0.f, 0.f, 0.f, 0.f};

    float4 k0, k1, v0, v1;               // in-flight staging registers
    int2   mm;

    auto LOAD = [&](int t) {             // coalesced: 4x dwordx4 + 1x dwordx2
        const int s = s0 + t * 32 + 2 * p;
        k0 = *(const float4*)(Kb + (size_t)s       * DIM + d0);
        k1 = *(const float4*)(Kb + (size_t)(s + 1) * DIM + d0);
        v0 = *(const float4*)(Vb + (size_t)s       * DIM + d0);
        v1 = *(const float4*)(Vb + (size_t)(s + 1) * DIM + d0);
        mm = *(const int2*)(mb + s);
    };

    auto STORE = [&](int buf) {          // featmap + mask + pack -> transposed LDS
        unsigned int* KT = lds + buf * 2560;
        unsigned int* VT = KT + 1280;
        const float ka[4] = {k0.x, k0.y, k0.z, k0.w};
        const float kb[4] = {k1.x, k1.y, k1.z, k1.w};
        const float va[4] = {v0.x, v0.y, v0.z, v0.w};
        const float vb[4] = {v1.x, v1.y, v1.z, v1.w};
        #pragma unroll
        for (int i = 0; i < 4; ++i) {
            float f0 = mm.x ? featmap(ka[i]) : 0.0f;
            float f1 = mm.y ? featmap(kb[i]) : 0.0f;
            ksum4[i] += f0 + f1;         // fp32 ksum from pre-rounded kf
            KT[(d0 + i) * PITCH + p] = pack2(f0, f1);
            VT[(d0 + i) * PITCH + p] = pack2(va[i], vb[i]);
        }
    };

    auto COMPUTE = [&](int buf) {        // 5x ds_read_b128 + 4x MFMA
        const unsigned int* KT = lds + buf * 2560;
        const unsigned int* VT = KT + 1280;
        const bf16x8 af = *(const bf16x8*)&KT[(wave * 16 + r) * PITCH + 4 * g];
        #pragma unroll
        for (int nt = 0; nt < 4; ++nt) {
            const bf16x8 bf = *(const bf16x8*)&VT[(nt * 16 + r) * PITCH + 4 * g];
            acc[nt] = __builtin_amdgcn_mfma_f32_16x16x32_bf16(af, bf, acc[nt], 0, 0, 0);
        }
    };

    LOAD(0);
    STORE(0);
    __syncthreads();
    for (int t = 0; t < ntile; ++t) {
        const int cur = t & 1;
        if (t + 1 < ntile) LOAD(t + 1);      // issue next tile's global loads
        COMPUTE(cur);                        // overlaps load latency
        if (t + 1 < ntile) STORE(cur ^ 1);   // waits vmcnt, writes other buffer
        __syncthreads();
    }

    // C layout: col = lane&15, row = (lane>>4)*4 + reg (verified)
    float* dst = partM + (size_t)(bh * nchunk + chunk) * MSTRIDE;
    #pragma unroll
    for (int nt = 0; nt < 4; ++nt)
        #pragma unroll
        for (int j = 0; j < 4; ++j)
            dst[(wave * 16 + g * 4 + j) * 64 + nt * 16 + r] = acc[nt][j];

    // ksum: reduce the 16 s-pair partials per d (reuse LDS; loop ended with barrier)
    float* kr = (float*)lds;                 // [64][16] fp32
    #pragma unroll
    for (int i = 0; i < 4; ++i) kr[(d0 + i) * 16 + p] = ksum4[i];
    __syncthreads();
    if (tid < 64) {
        float s = 0.0f;
        #pragma unroll
        for (int q = 0; q < 16; ++q) s += kr[tid * 16 + q];
        dst[4096 + tid] = s;
    }
}

// ---------------------------------------------------------------------------
// Phase 1b: reduce chunk partials -> final M + ksum per bh.
// Grid (4, NBH): 260 float4-quads per block -> all 256 CUs busy.
// ---------------------------------------------------------------------------
__global__ __launch_bounds__(256) void k_reduce(
    const float* __restrict__ partM, float* __restrict__ finalM, int nchunk)
{
    const int bh  = blockIdx.y;
    const int tid = threadIdx.x;
    const float4* src = (const float4*)(partM + (size_t)bh * nchunk * MSTRIDE);
    float4* dst = (float4*)(finalM + (size_t)bh * MSTRIDE);
    const int qend = blockIdx.x * 260 + 260;
    for (int q = blockIdx.x * 260 + tid; q < qend; q += 256) {
        float4 s = src[q];
        for (int c = 1; c < nchunk; ++c) {
            float4 t = src[(size_t)c * (MSTRIDE / 4) + q];
            s.x += t.x; s.y += t.y; s.z += t.z; s.w += t.w;
        }
        dst[q] = s;
    }
}

// ---------------------------------------------------------------------------
// Phase 2: out[q][e] = (Qf[q] . M[:,e]) / max(Qf[q] . ksum, eps)
// bf16 MFMA 16x16x32; contraction dim d is memory-contiguous for Q.
// ---------------------------------------------------------------------------
__global__ __launch_bounds__(256, 4) void k_phase2(
    const float* __restrict__ Q, const float* __restrict__ finalM,
    float* __restrict__ out)
{
    const int bh   = blockIdx.y;
    const int tid  = threadIdx.x;
    const int wave = tid >> 6;
    const int lane = tid & 63;
    const int r    = lane & 15;          // A row / B col / store col
    const int g    = lane >> 4;          // k-group

    const float* Mb = finalM + (size_t)bh * MSTRIDE;

    // B frags: lane holds M[kk*32 + g*8 + j][nt*16 + r]; ksum slices in fp32
    bf16x8 bfr[4][2];
    float  ksl[2][8];
    #pragma unroll
    for (int kk = 0; kk < 2; ++kk)
        #pragma unroll
        for (int j = 0; j < 8; ++j) {
            const int d = kk*32 + g*8 + j;
            ksl[kk][j] = Mb[4096 + d];
            #pragma unroll
            for (int nt = 0; nt < 4; ++nt)
                bfr[nt][kk][j] = (short)f2bf_u(Mb[d*64 + nt*16 + r]);
        }

    const int q0 = blockIdx.x * 64 + wave * 16;
    const float* Qrow = Q + (size_t)bh * SEQ * DIM + (size_t)(q0 + r) * DIM;

    // A frags (Qf) + fp32 norm partial
    bf16x8 afr[2];
    float z = 0.0f;
    #pragma unroll
    for (int kk = 0; kk < 2; ++kk) {
        float4 x0 = *(const float4*)(Qrow + kk*32 + g*8);
        float4 x1 = *(const float4*)(Qrow + kk*32 + g*8 + 4);
        const float qf[8] = {featmap(x0.x), featmap(x0.y), featmap(x0.z), featmap(x0.w),
                             featmap(x1.x), featmap(x1.y), featmap(x1.z), featmap(x1.w)};
        #pragma unroll
        for (int j = 0; j < 8; ++j) {
            z = fmaf(qf[j], ksl[kk][j], z);
            afr[kk][j] = (short)f2bf_u(qf[j]);
        }
    }
    // Z[row r] = sum over the 4 k-groups holding row r
    z += __shfl_xor(z, 16);
    z += __shfl_xor(z, 32);

    f32x4 acc[4];
    #pragma unroll
    for (int nt = 0; nt < 4; ++nt) acc[nt] = (f32x4){0.f, 0.f, 0.f, 0.f};
    #pragma unroll
    for (int kk = 0; kk < 2; ++kk)
        #pragma unroll
        for (int nt = 0; nt < 4; ++nt)
            acc[nt] = __builtin_amdgcn_mfma_f32_16x16x32_bf16(
                afr[kk], bfr[nt][kk], acc[nt], 0, 0, 0);

    // C layout: col = lane&15, row = (lane>>4)*4 + reg
    float rinv[4];
    #pragma unroll
    for (int j = 0; j < 4; ++j) {
        const float zc = __shfl(z, g*4 + j);   // lane idx < 16 holds Z[idx]
        rinv[j] = 1.0f / fmaxf(zc, FEPS);
    }
    float* Ob = out + (size_t)bh * SEQ * DIM;
    #pragma unroll
    for (int nt = 0; nt < 4; ++nt)
        #pragma unroll
        for (int j = 0; j < 4; ++j)
            Ob[(size_t)(q0 + g*4 + j) * DIM + nt*16 + r] = acc[nt][j] * rinv[j];
}

extern "C" void kernel_launch(void* const* d_in, const int* in_sizes, int n_in,
                              void* d_out, int out_size, void* d_ws, size_t ws_size,
                              hipStream_t stream) {
    const float* Q    = (const float*)d_in[0];
    const float* K    = (const float*)d_in[1];
    const float* V    = (const float*)d_in[2];
    const int*   mask = (const int*)d_in[3];   // numpy bool -> int32
    float* out = (float*)d_out;
    float* ws  = (float*)d_ws;

    int nchunk = 16;
    while (nchunk > 1 &&
           ws_size < (size_t)(NBH * nchunk + NBH) * MSTRIDE * sizeof(float))
        nchunk >>= 1;
    const int rows = SEQ / nchunk;

    float* partM  = ws;
    float* finalM = ws + (size_t)NBH * nchunk * MSTRIDE;

    k_phase1<<<dim3(nchunk, NBH), 256, 0, stream>>>(K, V, mask, partM, nchunk, rows);
    k_reduce<<<dim3(4, NBH), 256, 0, stream>>>(partM, finalM, nchunk);
    k_phase2<<<dim3(64, NBH), 256, 0, stream>>>(Q, finalM, out);
}